// Round 1
// baseline (249.050 us; speedup 1.0000x reference)
//
#include <hip/hip_runtime.h>

typedef unsigned short ushort_t;
typedef unsigned int uint32;
typedef __bf16 bf16x8 __attribute__((ext_vector_type(8)));
typedef float f32x4 __attribute__((ext_vector_type(4)));

#define NB 4
#define NH 16
#define NS 4096
#define ND 64
#define NBH 64
#define EPSF 1e-6f

#define CH1 16
#define ROWS1 (NS / CH1)          // 256 rows per pass1 block
#define P2R 128
#define LDJ 72                    // ushort row stride (144 B: 16B-aligned -> ds_read_b128)
#define LDJW 36
#define BTSZ (80 * 64)            // ushorts per B-panel per bh

__device__ __forceinline__ float phi_f(float x) {
    // elu(x)+1 : x>0 ? x+1 : exp(x)
    return x > 0.0f ? x + 1.0f : __expf(x);
}
__device__ __forceinline__ ushort_t bf16_rn(float x) {
    uint32 u = __float_as_uint(x);
    uint32 r = (u + 0x7FFFu + ((u >> 16) & 1u)) >> 16;
    return (ushort_t)r;
}
__device__ __forceinline__ void split2(float x, ushort_t& h, ushort_t& l) {
    h = bf16_rn(x);
    float hf = __uint_as_float(((uint32)h) << 16);
    l = bf16_rn(x - hf);
}
union FragP { ushort_t s[8]; bf16x8 v; };
__device__ __forceinline__ bf16x8 ld_frag(const ushort_t* arr, int widx) {
    // widx is a 4-byte-word index, multiple of 4 -> 16B aligned -> ds_read_b128
    return *(const bf16x8*)((const uint32*)arr + widx);
}
__device__ __forceinline__ f32x4 mfma16(bf16x8 a, bf16x8 b, f32x4 c) {
    return __builtin_amdgcn_mfma_f32_16x16x32_bf16(a, b, c, 0, 0, 0);
}

// =====================================================================
// Pass 1: partial KV = phiK^T @ V over a 256-row chunk (+ partial k1).
// Split-fp32 (bf16 hi/lo, 3 MFMA per tile). phiK and V staged TRANSPOSED
// ([d or v][s], s-contiguous) as bf16 hi/lo.
// NEW: register prefetch of tile t+1 issued before the MFMA phase of
// tile t (convert happens in registers before the barrier), so HBM
// latency overlaps MFMA + barrier + next convert instead of being
// fully exposed. LDS row stride 72 -> ds_read_b128 fragment reads.
// LDS 36.9 KB -> 4 blocks/CU.
// =====================================================================
template<bool PART>
__global__ __launch_bounds__(256, 4)
void la_pass1(const float* __restrict__ Kin, const float* __restrict__ Vin,
              const float* __restrict__ Min, float* __restrict__ okv,
              float* __restrict__ ok1)
{
    const int t  = threadIdx.x;
    const int cx = blockIdx.x;
    const int bh = blockIdx.y;
    const int bb = bh >> 4;                   // H = 16
    const float* Kb = Kin + (long long)bh * NS * ND;
    const float* Vb = Vin + (long long)bh * NS * ND;
    const float* Mb = Min + (long long)bb * NS;

    __shared__ __align__(16) ushort_t skh[64 * LDJ], skl[64 * LDJ];
    __shared__ __align__(16) ushort_t svh[64 * LDJ], svl[64 * LDJ];

    const int p  = t & 31;                    // staging row-pair (rows 2p, 2p+1)
    const int c0 = (t >> 5) * 8;              // staging cols c0..c0+7
    const int wv = t >> 6;                    // wave id -> d-strip 16*wv
    const int m  = t & 15;
    const int q  = (t & 63) >> 4;

    const f32x4 zf = {0.f, 0.f, 0.f, 0.f};
    f32x4 acc0 = zf, acc1 = zf, acc2 = zf, acc3 = zf;
    float k1loc[8] = {0.f,0.f,0.f,0.f,0.f,0.f,0.f,0.f};

    const int s0 = cx * ROWS1;

    float4 ka, kb2, kc, kd, va, vb2, vc, vd;
    float m0, m1;
#define LOADT(tt) { \
        const int r0_ = s0 + (tt) * 64 + 2 * p; \
        const float* kp_ = Kb + (long long)r0_ * ND + c0; \
        const float* vp_ = Vb + (long long)r0_ * ND + c0; \
        ka  = *(const float4*)kp_;        kb2 = *(const float4*)(kp_ + 4); \
        kc  = *(const float4*)(kp_ + ND); kd  = *(const float4*)(kp_ + ND + 4); \
        va  = *(const float4*)vp_;        vb2 = *(const float4*)(vp_ + 4); \
        vc  = *(const float4*)(vp_ + ND); vd  = *(const float4*)(vp_ + ND + 4); \
        m0 = Mb[r0_]; m1 = Mb[r0_ + 1]; }

    LOADT(0);

    for (int tile = 0; tile < ROWS1 / 64; ++tile) {
        // ---- convert in registers (before barrier: fills the barrier wait) ----
        const float kr0[8] = {ka.x,ka.y,ka.z,ka.w,kb2.x,kb2.y,kb2.z,kb2.w};
        const float kr1[8] = {kc.x,kc.y,kc.z,kc.w,kd.x,kd.y,kd.z,kd.w};
        const float vr0[8] = {va.x,va.y,va.z,va.w,vb2.x,vb2.y,vb2.z,vb2.w};
        const float vr1[8] = {vc.x,vc.y,vc.z,vc.w,vd.x,vd.y,vd.z,vd.w};
        uint32 wkh[8], wkl[8], wvh[8], wvl[8];
        #pragma unroll
        for (int i = 0; i < 8; ++i) {
            const float x0 = phi_f(kr0[i]) * m0;
            const float x1 = phi_f(kr1[i]) * m1;
            k1loc[i] += x0 + x1;
            ushort_t h0, l0, h1, l1;
            split2(x0, h0, l0); split2(x1, h1, l1);
            wkh[i] = (uint32)h0 | ((uint32)h1 << 16);
            wkl[i] = (uint32)l0 | ((uint32)l1 << 16);
            split2(vr0[i], h0, l0); split2(vr1[i], h1, l1);
            wvh[i] = (uint32)h0 | ((uint32)h1 << 16);
            wvl[i] = (uint32)l0 | ((uint32)l1 << 16);
        }
        __syncthreads();                       // previous tile consumed -> LDS free
        #pragma unroll
        for (int i = 0; i < 8; ++i) {
            const int widx = (c0 + i) * LDJW + p;
            ((uint32*)skh)[widx] = wkh[i];
            ((uint32*)skl)[widx] = wkl[i];
            ((uint32*)svh)[widx] = wvh[i];
            ((uint32*)svl)[widx] = wvl[i];
        }
        if (tile + 1 < ROWS1 / 64) LOADT(tile + 1);   // prefetch next tile (overlaps MFMA)
        __syncthreads();
        #pragma unroll
        for (int ks = 0; ks < 2; ++ks) {
            const int fo = ks * 16 + q * 4;
            const bf16x8 ah = ld_frag(skh, (16 * wv + m) * LDJW + fo);
            const bf16x8 al = ld_frag(skl, (16 * wv + m) * LDJW + fo);
            {
                const bf16x8 fbh = ld_frag(svh, (0 + m) * LDJW + fo);
                const bf16x8 fbl = ld_frag(svl, (0 + m) * LDJW + fo);
                acc0 = mfma16(al, fbh, acc0); acc0 = mfma16(ah, fbl, acc0); acc0 = mfma16(ah, fbh, acc0);
            }
            {
                const bf16x8 fbh = ld_frag(svh, (16 + m) * LDJW + fo);
                const bf16x8 fbl = ld_frag(svl, (16 + m) * LDJW + fo);
                acc1 = mfma16(al, fbh, acc1); acc1 = mfma16(ah, fbl, acc1); acc1 = mfma16(ah, fbh, acc1);
            }
            {
                const bf16x8 fbh = ld_frag(svh, (32 + m) * LDJW + fo);
                const bf16x8 fbl = ld_frag(svl, (32 + m) * LDJW + fo);
                acc2 = mfma16(al, fbh, acc2); acc2 = mfma16(ah, fbl, acc2); acc2 = mfma16(ah, fbh, acc2);
            }
            {
                const bf16x8 fbh = ld_frag(svh, (48 + m) * LDJW + fo);
                const bf16x8 fbl = ld_frag(svl, (48 + m) * LDJW + fo);
                acc3 = mfma16(al, fbh, acc3); acc3 = mfma16(ah, fbl, acc3); acc3 = mfma16(ah, fbh, acc3);
            }
        }
    }
#undef LOADT

    // ---- store partial KV (D[row=q*4+i within strip][col=16nt+m]) ----
    const int dbase = 16 * wv + q * 4;
    if (PART) {
        float* outp = okv + (long long)(bh * CH1 + cx) * (ND * ND);
        #pragma unroll
        for (int i = 0; i < 4; ++i) {
            outp[(dbase + i) * ND +  0 + m] = acc0[i];
            outp[(dbase + i) * ND + 16 + m] = acc1[i];
            outp[(dbase + i) * ND + 32 + m] = acc2[i];
            outp[(dbase + i) * ND + 48 + m] = acc3[i];
        }
    } else {
        float* outp = okv + (long long)bh * (ND * ND);
        #pragma unroll
        for (int i = 0; i < 4; ++i) {
            atomicAdd(&outp[(dbase + i) * ND +  0 + m], acc0[i]);
            atomicAdd(&outp[(dbase + i) * ND + 16 + m], acc1[i]);
            atomicAdd(&outp[(dbase + i) * ND + 32 + m], acc2[i]);
            atomicAdd(&outp[(dbase + i) * ND + 48 + m], acc3[i]);
        }
    }
    // ---- k1 partial reduce through LDS (stride-33 floats: 2-way banks) ----
    __syncthreads();
    float* red = (float*)skh;                  // 64*33 floats = 8448 B <= 9216 B
    #pragma unroll
    for (int i = 0; i < 8; ++i) red[(c0 + i) * 33 + p] = k1loc[i];
    __syncthreads();
    if (t < 64) {
        float s = 0.f;
        #pragma unroll
        for (int pp = 0; pp < 32; ++pp) s += red[t * 33 + pp];
        if (PART) ok1[(bh * CH1 + cx) * ND + t] = s;
        else      atomicAdd(&ok1[bh * ND + t], s);
    }
}

// =====================================================================
// Reduce: sum CH1 partial KV tiles + k1 partials, emit the pass-2 B
// panel directly as split bf16 hi/lo, TRANSPOSED ([n=v][k=d], 80 rows:
// row 64 = k1, rows 65..79 = 0). Pass 2 fragment-loads it from global.
// =====================================================================
__global__ __launch_bounds__(256)
void la_reduce(const float* __restrict__ pkv, const float* __restrict__ pk1,
               ushort_t* __restrict__ BTh, ushort_t* __restrict__ BTl)
{
    const int t = threadIdx.x;
    const int bh = blockIdx.x;
    const float4* src = (const float4*)(pkv + (long long)bh * CH1 * ND * ND);
    float4 a[4];
    #pragma unroll
    for (int i = 0; i < 4; ++i) { a[i].x = 0.f; a[i].y = 0.f; a[i].z = 0.f; a[i].w = 0.f; }
    for (int c = 0; c < CH1; ++c) {
        #pragma unroll
        for (int i = 0; i < 4; ++i) {
            const float4 v = src[c * 1024 + t + 256 * i];
            a[i].x += v.x; a[i].y += v.y; a[i].z += v.z; a[i].w += v.w;
        }
    }
    ushort_t* oh = BTh + (long long)bh * BTSZ;
    ushort_t* ol = BTl + (long long)bh * BTSZ;
    #pragma unroll
    for (int i = 0; i < 4; ++i) {
        const int e4 = t + 256 * i;            // float4 index within 64x64 tile
        const int d  = e4 >> 4;                // row of KV
        const int v0 = (e4 & 15) * 4;          // col of KV
        const float vals[4] = {a[i].x, a[i].y, a[i].z, a[i].w};
        #pragma unroll
        for (int j = 0; j < 4; ++j) {
            ushort_t h, l; split2(vals[j], h, l);
            oh[(v0 + j) * ND + d] = h;         // transposed: BT[v][d]
            ol[(v0 + j) * ND + d] = l;
        }
    }
    if (t < ND) {
        float s = 0.f;
        for (int c = 0; c < CH1; ++c) s += pk1[(bh * CH1 + c) * ND + t];
        ushort_t h, l; split2(s, h, l);
        oh[64 * ND + t] = h; ol[64 * ND + t] = l;
    }
    for (int z = t; z < 15 * 64; z += 256) { oh[65 * ND + z] = 0; ol[65 * ND + z] = 0; }
}

// Fallback-path converter (atomic-accumulated fp32 KV/k1 -> BT panels)
__global__ __launch_bounds__(256)
void la_convert(const float* __restrict__ kv, const float* __restrict__ k1,
                ushort_t* __restrict__ BTh, ushort_t* __restrict__ BTl)
{
    const int t = threadIdx.x;
    const int bh = blockIdx.x;
    const float* kvb = kv + (long long)bh * ND * ND;
    ushort_t* oh = BTh + (long long)bh * BTSZ;
    ushort_t* ol = BTl + (long long)bh * BTSZ;
    for (int e = t; e < ND * ND; e += 256) {
        const int d = e >> 6, v = e & 63;
        ushort_t h, l; split2(kvb[e], h, l);
        oh[v * ND + d] = h; ol[v * ND + d] = l;
    }
    if (t < ND) { ushort_t h, l; split2(k1[bh * ND + t], h, l); oh[64 * ND + t] = h; ol[64 * ND + t] = l; }
    for (int z = t; z < 15 * 64; z += 256) { oh[65 * ND + z] = 0; ol[65 * ND + z] = 0; }
}

// =====================================================================
// Pass 2: out = (phiQ @ [KV | k1]) / norm, split-fp32 MFMA.
// NEW: LDS-free and barrier-free. A fragments (row=m, 8 contiguous
// k-elements) built straight from global float4 loads of Q + in-register
// phi/split. B fragments loaded from the precomputed global bf16 hi/lo
// KV^T panels (20 KB/bh -> L1/L2 resident). Latency hidden by occupancy
// (no LDS cap, no __syncthreads).
// =====================================================================
__global__ __launch_bounds__(256, 4)
void la_pass2(const float* __restrict__ Qin, const ushort_t* __restrict__ BTh,
              const ushort_t* __restrict__ BTl, float* __restrict__ Out)
{
    const int t  = threadIdx.x;
    const int bh = blockIdx.y;
    const int s0 = blockIdx.x * P2R;
    const long long base = (long long)bh * NS * ND;
    const int wv = t >> 6;
    const int m  = t & 15;
    const int q  = (t & 63) >> 4;
    const int lane = t & 63;
    const ushort_t* Bh = BTh + (long long)bh * BTSZ;
    const ushort_t* Bl = BTl + (long long)bh * BTSZ;

    // ---- A fragments: phi(q/8) hi/lo, direct from global ----
    bf16x8 aH[2][2], aL[2][2];
    #pragma unroll
    for (int mtl = 0; mtl < 2; ++mtl) {
        const int row = s0 + 32 * wv + 16 * mtl + m;
        const float* qp = Qin + base + (long long)row * ND;
        #pragma unroll
        for (int ks = 0; ks < 2; ++ks) {
            const float4 x0 = *(const float4*)(qp + ks * 32 + q * 8);
            const float4 x1 = *(const float4*)(qp + ks * 32 + q * 8 + 4);
            const float xs[8] = {x0.x,x0.y,x0.z,x0.w,x1.x,x1.y,x1.z,x1.w};
            FragP fh, fl;
            #pragma unroll
            for (int i = 0; i < 8; ++i) {
                ushort_t h, l; split2(phi_f(xs[i] * 0.125f), h, l);
                fh.s[i] = h; fl.s[i] = l;
            }
            aH[mtl][ks] = fh.v; aL[mtl][ks] = fl.v;
        }
    }

    const f32x4 zf = {0.f, 0.f, 0.f, 0.f};
    f32x4 acc[2][5];
    #pragma unroll
    for (int a = 0; a < 2; ++a)
        #pragma unroll
        for (int b = 0; b < 5; ++b) acc[a][b] = zf;

    #pragma unroll
    for (int ks = 0; ks < 2; ++ks) {
        #pragma unroll
        for (int nt = 0; nt < 5; ++nt) {
            const int bo = (16 * nt + m) * ND + ks * 32 + q * 8;   // 16B aligned
            const bf16x8 fbh = *(const bf16x8*)(Bh + bo);
            const bf16x8 fbl = *(const bf16x8*)(Bl + bo);
            acc[0][nt] = mfma16(aL[0][ks], fbh, acc[0][nt]);
            acc[0][nt] = mfma16(aH[0][ks], fbl, acc[0][nt]);
            acc[0][nt] = mfma16(aH[0][ks], fbh, acc[0][nt]);
            acc[1][nt] = mfma16(aL[1][ks], fbh, acc[1][nt]);
            acc[1][nt] = mfma16(aH[1][ks], fbl, acc[1][nt]);
            acc[1][nt] = mfma16(aH[1][ks], fbh, acc[1][nt]);
        }
    }

    // ---- epilogue: normalizer in acc[*][4] col 0 (lane m==0) ----
    float* outb = Out + base;
    #pragma unroll
    for (int mtl = 0; mtl < 2; ++mtl) {
        const int rbase = s0 + 32 * wv + 16 * mtl + q * 4;
        #pragma unroll
        for (int i = 0; i < 4; ++i) {
            const float nv = __shfl(acc[mtl][4][i], lane & 48, 64);
            const float rn = 1.0f / (nv + EPSF);
            const long long ro = (long long)(rbase + i) * ND;
            outb[ro +  0 + m] = acc[mtl][0][i] * rn;
            outb[ro + 16 + m] = acc[mtl][1][i] * rn;
            outb[ro + 32 + m] = acc[mtl][2][i] * rn;
            outb[ro + 48 + m] = acc[mtl][3][i] * rn;
        }
    }
}

extern "C" void kernel_launch(void* const* d_in, const int* in_sizes, int n_in,
                              void* d_out, int out_size, void* d_ws, size_t ws_size,
                              hipStream_t stream)
{
    const float* Q = (const float*)d_in[0];
    const float* K = (const float*)d_in[1];
    const float* V = (const float*)d_in[2];
    const float* M = (const float*)d_in[3];
    float* Out = (float*)d_out;

    const size_t partf = (size_t)NBH * CH1 * ND * ND;   // 4,194,304 floats
    const size_t pk1f  = (size_t)NBH * CH1 * ND;        //    65,536
    const size_t kvf   = (size_t)NBH * ND * ND;         //   262,144
    const size_t k1f   = (size_t)NBH * ND;              //     4,096
    const size_t btu   = (size_t)NBH * BTSZ;            //   327,680 ushorts per panel
    const size_t need  = (partf + pk1f) * sizeof(float) + 2 * btu * sizeof(ushort_t); // ~18.4 MB

    if (ws_size >= need) {
        float* PKV = (float*)d_ws;
        float* PK1 = PKV + partf;
        ushort_t* BThp = (ushort_t*)(PK1 + pk1f);
        ushort_t* BTlp = BThp + btu;
        la_pass1<true><<<dim3(CH1, NBH), dim3(256), 0, stream>>>(K, V, M, PKV, PK1);
        la_reduce<<<dim3(NBH), dim3(256), 0, stream>>>(PKV, PK1, BThp, BTlp);
        la_pass2<<<dim3(NS / P2R, NBH), dim3(256), 0, stream>>>(Q, BThp, BTlp, Out);
    } else {
        float* KVb = (float*)d_ws;
        float* K1b = KVb + kvf;
        ushort_t* BThp = (ushort_t*)(K1b + k1f);
        ushort_t* BTlp = BThp + btu;
        hipMemsetAsync(d_ws, 0, (kvf + k1f) * sizeof(float), stream);
        la_pass1<false><<<dim3(CH1, NBH), dim3(256), 0, stream>>>(K, V, M, KVb, K1b);
        la_convert<<<dim3(NBH), dim3(256), 0, stream>>>(KVb, K1b, BThp, BTlp);
        la_pass2<<<dim3(NS / P2R, NBH), dim3(256), 0, stream>>>(Q, BThp, BTlp, Out);
    }
}